// Round 1
// baseline (262.261 us; speedup 1.0000x reference)
//
#include <hip/hip_runtime.h>

// Problem: B=8, C=256, N=2048, fp32.
// attn_b = (M_b Wk / S) x_b + (M_b bk / S) 1^T
//   M_b = Wv G_b Wq^T + (Wv sx_b) bq^T + bv (Wq sx_b + N bq)^T   (last two folded)
//   G_b = x_b x_b^T,  sx_b = rowsum_n(x_b)
//   S   = sum_b (Wq sx_b + N bq) . (Wk sx_b + N bk)
//
// Workspace layout (floats), total ~6.33 MB:
//   G   @ 0        (8*256*256)   [zeroed; reused as Ascaled after Kmid1]
//   T1  @ 524288   (8*256*256)
//   M   @ 1048576  (8*256*256)
//   sx  @ 1572864  (2048)
//   wqsx@ 1574912  (2048)
//   tq  @ 1576960  (2048)   tq = Wq sx + N bq
//   wvsx@ 1579008  (2048)
//   c   @ 1581056  (2048)
//   S   @ 1583104  (1)      [zeroed]

#define TILE 64
#define BK 16

// ---------------- rowsum over n: sx[b*C+c] = sum_n x[b,c,n] ----------------
__launch_bounds__(256)
__global__ void rowsum_kernel(const float* __restrict__ x, float* __restrict__ sx) {
    const int row = blockIdx.x;                 // 0..B*C-1
    const float* xr = x + (long)row * 2048;
    const int t = threadIdx.x;
    float s = 0.0f;
    #pragma unroll
    for (int i = 0; i < 8; ++i) s += xr[t + 256 * i];   // coalesced
    __shared__ float red[256];
    red[t] = s; __syncthreads();
    for (int h = 128; h > 0; h >>= 1) {
        if (t < h) red[t] += red[t + h];
        __syncthreads();
    }
    if (t == 0) sx[row] = red[0];
}

// ---- per-batch stats: wqsx = Wq sx_b, wvsx = Wv sx_b, tq = wqsx + N bq,
// ---- S += (wqsx + N bq) . (Wk sx_b + N bk) ----
__launch_bounds__(256)
__global__ void stats_kernel(const float* __restrict__ Wq, const float* __restrict__ bq,
                             const float* __restrict__ Wk, const float* __restrict__ bk,
                             const float* __restrict__ Wv, const float* __restrict__ sx,
                             float* __restrict__ wqsx, float* __restrict__ tq,
                             float* __restrict__ wvsx, float* __restrict__ Sacc) {
    const int b = blockIdx.x;
    const int o = threadIdx.x;                  // 256 threads, one output channel each
    __shared__ float ssx[256];
    ssx[o] = sx[b * 256 + o];
    __syncthreads();
    float aq = 0.0f, ak = 0.0f, av = 0.0f;
    #pragma unroll 4
    for (int c = 0; c < 256; ++c) {
        const float s = ssx[c];
        aq = fmaf(Wq[o * 256 + c], s, aq);
        ak = fmaf(Wk[o * 256 + c], s, ak);
        av = fmaf(Wv[o * 256 + c], s, av);
    }
    wqsx[b * 256 + o] = aq;
    wvsx[b * 256 + o] = av;
    const float tqo = aq + 2048.0f * bq[o];
    const float tko = ak + 2048.0f * bk[o];
    tq[b * 256 + o] = tqo;
    __shared__ float red[256];
    red[o] = tqo * tko; __syncthreads();
    for (int h = 128; h > 0; h >>= 1) {
        if (o < h) red[o] += red[o + h];
        __syncthreads();
    }
    if (o == 0) atomicAdd(Sacc, red[0]);
}

// ---- c_b[o] = (1/S) * sum_c M_b[o,c] bk[c] ----
__launch_bounds__(256)
__global__ void cvec_kernel(const float* __restrict__ M, const float* __restrict__ bk,
                            const float* __restrict__ Sptr, float* __restrict__ cvec) {
    const int b = blockIdx.x;
    const int o = threadIdx.x;
    const float* Mr = M + (long)b * 65536 + (long)o * 256;
    float s = 0.0f;
    #pragma unroll 4
    for (int c = 0; c < 256; ++c) s = fmaf(Mr[c], bk[c], s);
    cvec[b * 256 + o] = s / Sptr[0];
}

// ---------------- generic tiled fp32 GEMM: D = A @ B (+ epilogue) ----------------
// 64x64 tile per 256-thread block, 4x4 per thread, BK=16.
// A row-major [rows][K] (lda), per-batch stride aBatch.
// TRANSB=false: B[k][j] = Bmat[k*ldb + j]; TRANSB=true: B[k][j] = Bmat[j*ldb + k].
// EPI: 0 store; 1 +e1[b,r]*e2[col]+e3[r]*e4[b,col]; 2 *(1/S); 3 +e1[b,r]; 4 atomicAdd.
template <bool TRANSB, int EPI>
__launch_bounds__(256)
__global__ void gemm64(const float* __restrict__ Amat, long aBatch, int lda,
                       const float* __restrict__ Bmat, long bBatch, int ldb,
                       float* __restrict__ Dmat, long dBatch, int ldd,
                       int K, int kSplit,
                       const float* __restrict__ e1, const float* __restrict__ e2,
                       const float* __restrict__ e3, const float* __restrict__ e4,
                       const float* __restrict__ Sptr) {
    __shared__ float ldsA[BK][TILE];
    __shared__ float ldsB[BK][TILE];

    const int b  = blockIdx.z / kSplit;
    const int ks = blockIdx.z % kSplit;
    const int kLen = K / kSplit;
    const int kBegin = ks * kLen;
    const int kEnd = kBegin + kLen;

    const int r0 = blockIdx.y * TILE;
    const int j0 = blockIdx.x * TILE;

    const float* A = Amat + (long)b * aBatch;
    const float* B = Bmat + (long)b * bBatch;
    float* D = Dmat + (long)b * dBatch;

    const int t  = threadIdx.x;
    const int tx = t & 15, ty = t >> 4;
    // staging maps
    const int srl = t >> 2;          // 0..63: row (A) / col (B^T)
    const int sjj = (t & 3) * 4;     // k sub-offset
    const int bkl = t >> 4;          // 0..15: k row for direct-B
    const int bjl = (t & 15) * 4;    // col offset for direct-B

    float acc[4][4] = {};

    for (int kk = kBegin; kk < kEnd; kk += BK) {
        // A panel: 64 rows x 16 k, transposed store -> ldsA[k][row]
        const float4 a4 = *(const float4*)&A[(long)(r0 + srl) * lda + kk + sjj];
        ldsA[sjj + 0][srl] = a4.x; ldsA[sjj + 1][srl] = a4.y;
        ldsA[sjj + 2][srl] = a4.z; ldsA[sjj + 3][srl] = a4.w;
        if (TRANSB) {
            const float4 b4 = *(const float4*)&B[(long)(j0 + srl) * ldb + kk + sjj];
            ldsB[sjj + 0][srl] = b4.x; ldsB[sjj + 1][srl] = b4.y;
            ldsB[sjj + 2][srl] = b4.z; ldsB[sjj + 3][srl] = b4.w;
        } else {
            const float4 b4 = *(const float4*)&B[(long)(kk + bkl) * ldb + j0 + bjl];
            *(float4*)&ldsB[bkl][bjl] = b4;
        }
        __syncthreads();
        #pragma unroll
        for (int k = 0; k < BK; ++k) {
            const float4 a = *(const float4*)&ldsA[k][ty * 4];
            const float4 bb = *(const float4*)&ldsB[k][tx * 4];
            const float ar[4] = {a.x, a.y, a.z, a.w};
            const float br[4] = {bb.x, bb.y, bb.z, bb.w};
            #pragma unroll
            for (int i = 0; i < 4; ++i)
                #pragma unroll
                for (int j = 0; j < 4; ++j)
                    acc[i][j] = fmaf(ar[i], br[j], acc[i][j]);
        }
        __syncthreads();
    }

    const float invS = (EPI == 2) ? (1.0f / Sptr[0]) : 1.0f;
    #pragma unroll
    for (int i = 0; i < 4; ++i) {
        const int r = r0 + ty * 4 + i;
        if (EPI == 4) {
            #pragma unroll
            for (int j = 0; j < 4; ++j)
                atomicAdd(&D[(long)r * ldd + j0 + tx * 4 + j], acc[i][j]);
        } else {
            float v[4];
            #pragma unroll
            for (int j = 0; j < 4; ++j) {
                const int col = j0 + tx * 4 + j;
                float val = acc[i][j];
                if (EPI == 1) val += e1[(long)b * 256 + r] * e2[col] + e3[r] * e4[(long)b * 256 + col];
                if (EPI == 2) val *= invS;
                if (EPI == 3) val += e1[(long)b * 256 + r];
                v[j] = val;
            }
            *(float4*)&D[(long)r * ldd + j0 + tx * 4] = make_float4(v[0], v[1], v[2], v[3]);
        }
    }
}

extern "C" void kernel_launch(void* const* d_in, const int* in_sizes, int n_in,
                              void* d_out, int out_size, void* d_ws, size_t ws_size,
                              hipStream_t stream) {
    const float* x  = (const float*)d_in[0];
    const float* Wq = (const float*)d_in[1];
    const float* bq = (const float*)d_in[2];
    const float* Wk = (const float*)d_in[3];
    const float* bk = (const float*)d_in[4];
    const float* Wv = (const float*)d_in[5];
    const float* bv = (const float*)d_in[6];
    float* out = (float*)d_out;
    float* ws  = (float*)d_ws;

    const int B = 8, C = 256, N = 2048;
    float* G    = ws;                 // [B,C,C], reused as Ascaled later
    float* T1   = ws + 524288;        // [B,C,C]
    float* M    = ws + 1048576;       // [B,C,C]
    float* sx   = ws + 1572864;       // [B,C]
    float* wqsx = ws + 1574912;       // [B,C]
    float* tq   = ws + 1576960;       // [B,C]
    float* wvsx = ws + 1579008;       // [B,C]
    float* cvec = ws + 1581056;       // [B,C]
    float* S    = ws + 1583104;       // [1]
    float* Asc  = G;

    hipMemsetAsync(G, 0, (size_t)B * C * C * sizeof(float), stream);
    hipMemsetAsync(S, 0, sizeof(float), stream);

    rowsum_kernel<<<dim3(B * C), 256, 0, stream>>>(x, sx);
    stats_kernel<<<dim3(B), 256, 0, stream>>>(Wq, bq, Wk, bk, Wv, sx, wqsx, tq, wvsx, S);

    // G_b = x_b x_b^T  (K=N, split-K=4, atomic combine)
    gemm64<true, 4><<<dim3(4, 4, B * 4), 256, 0, stream>>>(
        x, (long)C * N, N, x, (long)C * N, N, G, (long)C * C, C,
        N, 4, nullptr, nullptr, nullptr, nullptr, nullptr);

    // T1 = Wv @ G_b
    gemm64<false, 0><<<dim3(4, 4, B), 256, 0, stream>>>(
        Wv, 0, C, G, (long)C * C, C, T1, (long)C * C, C,
        C, 1, nullptr, nullptr, nullptr, nullptr, nullptr);

    // M_b = T1 @ Wq^T + wvsx_b (x) bq + bv (x) tq_b
    gemm64<true, 1><<<dim3(4, 4, B), 256, 0, stream>>>(
        T1, (long)C * C, C, Wq, 0, C, M, (long)C * C, C,
        C, 1, wvsx, bq, bv, tq, nullptr);

    // c_b = (M_b bk) / S
    cvec_kernel<<<dim3(B), 256, 0, stream>>>(M, bk, S, cvec);

    // Asc_b = (M_b @ Wk) / S
    gemm64<false, 2><<<dim3(4, 4, B), 256, 0, stream>>>(
        M, (long)C * C, C, Wk, 0, C, Asc, (long)C * C, C,
        C, 1, nullptr, nullptr, nullptr, nullptr, S);

    // out_b = Asc_b @ x_b + c_b
    gemm64<false, 3><<<dim3(N / 64, 4, B), 256, 0, stream>>>(
        Asc, (long)C * C, C, x, (long)C * N, N, out, (long)C * N, N,
        C, 1, cvec, nullptr, nullptr, nullptr, nullptr);
}